// Round 9
// baseline (505.994 us; speedup 1.0000x reference)
//
#include <hip/hip_runtime.h>

typedef unsigned short u16;
typedef __attribute__((ext_vector_type(8))) short short8;
typedef __attribute__((ext_vector_type(4))) float f32x4;

#define MFMA16(a, b, c) __builtin_amdgcn_mfma_f32_16x16x32_bf16((a), (b), (c), 0, 0, 0)

// ---- workspace layout (bytes) ----
#define OFF_BIAS 0            // fp32 [12][64][64]      = 196608
#define OFF_SCALES 196608     // fp32 [12]              (64 B slot)
#define OFF_RPB 196672        // fp32 [225][12]         = 10800 (slot to 207616)
#define OFF_QKVF 207616       // bf16 frag-ordered qkv weights = 884736
#define OFF_PROJF 1092352     // bf16 frag-ordered proj weights = 294912 (end 1387264)
#define OFF_XF 1387264        // bf16 fragment-ordered x: 1024 * 24576 u16 = 50331648
#define WS_NEED (1387264UL + 50331648UL)

// qkvF layout: frag(h,m,t,jn) at ((h*3+m)*24 + 2*t + jn)*512 + lane*8   (u16 units)
// projF layout: frag(w,t,jn)  at (w*72 + t*6 + jn)*512 + lane*8
// xF layout:    frag(t,i)     at ((t*4+i)*64 + lane)*8  within window slab of 24576

__device__ __forceinline__ u16 f2bf(float f) {
  unsigned x = __float_as_uint(f);
  return (u16)((x + 0x7fffu + ((x >> 16) & 1u)) >> 16);  // RNE, finite values only
}

// ================= prep: CPB MLP, one block per table entry (225 blocks) =================
__global__ __launch_bounds__(256) void prep_cpb(const float* __restrict__ tab, const float* __restrict__ w1,
                                                const float* __restrict__ b1, const float* __restrict__ w2,
                                                const float* __restrict__ b2, float* __restrict__ rpb) {
  const int t = blockIdx.x;   // 0..224
  const int tid = threadIdx.x;
  const float t0 = tab[2 * t], t1 = tab[2 * t + 1];
  float acc[12];
#pragma unroll
  for (int h = 0; h < 12; ++h) acc[h] = 0.f;
  for (int j = tid; j < 512; j += 256) {
    const float hv = fmaxf(t0 * w1[j] + t1 * w1[512 + j] + b1[j], 0.f);
#pragma unroll
    for (int h = 0; h < 12; ++h) acc[h] += hv * w2[j * 12 + h];
  }
#pragma unroll
  for (int h = 0; h < 12; ++h)
#pragma unroll
    for (int off = 1; off < 64; off <<= 1) acc[h] += __shfl_xor(acc[h], off);
  __shared__ float red[4][12];
  const int wave = tid >> 6;
  if ((tid & 63) == 0) {
#pragma unroll
    for (int h = 0; h < 12; ++h) red[wave][h] = acc[h];
  }
  __syncthreads();
  if (tid < 12) rpb[t * 12 + tid] = red[0][tid] + red[1][tid] + red[2][tid] + red[3][tid] + b2[tid];
}

// ================= unified prep =================
// bid 0..1023      : x window -> bf16 fragment-ordered xF (LDS-staged, coalesced both sides)
// bid 1024..1131   : qkv_w 64x64 tiles (6x18) -> frag-ordered qkvF
// bid 1132..1167   : proj_w tiles (6x6) -> frag-ordered projF
// bid 1168         : scales
// bid 1169..1184   : bias gather from rpb (256 p each)
__global__ __launch_bounds__(256) void prep_all(const float* __restrict__ x,
                                                const float* __restrict__ qkv_w,
                                                const float* __restrict__ proj_w,
                                                const float* __restrict__ logit_scale,
                                                const float* __restrict__ rpb,
                                                const int* __restrict__ rpb_idx,
                                                u16* __restrict__ xF, u16* __restrict__ qkvF,
                                                u16* __restrict__ projF, float* __restrict__ scales,
                                                float* __restrict__ bias, int bid0) {
  __shared__ __align__(16) u16 sm[24576];  // 48 KB, unioned per branch
  const int bid = blockIdx.x + bid0;
  const int tid = threadIdx.x;
  if (bid < 1024) {
    // ---- stage x window (fp32 -> bf16, swizzled, coalesced) ----
    const float4* x4 = reinterpret_cast<const float4*>(x + (long)bid * 24576);
#pragma unroll
    for (int it = 0; it < 12; ++it) {
      const int c = it * 256 + tid;  // 8-u16 chunk id, 0..3071
      const float4 a = x4[2 * c];
      const float4 b = x4[2 * c + 1];
      short8 v;
      v[0] = (short)f2bf(a.x); v[1] = (short)f2bf(a.y); v[2] = (short)f2bf(a.z); v[3] = (short)f2bf(a.w);
      v[4] = (short)f2bf(b.x); v[5] = (short)f2bf(b.y); v[6] = (short)f2bf(b.z); v[7] = (short)f2bf(b.w);
      const int row = c / 48;
      *reinterpret_cast<short8*>(sm + ((c * 8) ^ ((row & 7) << 3))) = v;
    }
    __syncthreads();
    // ---- emit fragment-ordered (coalesced writes) ----
    u16* dst = xF + (long)bid * 24576;
#pragma unroll
    for (int it = 0; it < 12; ++it) {
      const int slot = it * 256 + tid;           // 0..3071 = 48 frags x 64 lanes
      const int f = slot >> 6, l = slot & 63;
      const int row = 16 * (f & 3) + (l & 15);
      const int k0 = (f >> 2) * 32 + (l >> 4) * 8;
      const short8 v = *reinterpret_cast<const short8*>(sm + ((row * 384 + k0) ^ ((row & 7) << 3)));
      *reinterpret_cast<short8*>(dst + slot * 8) = v;
    }
  } else if (bid < 1168) {
    u16(*tile)[66] = reinterpret_cast<u16(*)[66]>(sm);  // pad 66: column reads 2-way (free)
    const float* src;
    int W, rt, ct;
    const bool isqkv = bid < 1132;
    if (isqkv) {
      const int b = bid - 1024;
      src = qkv_w; W = 1152; rt = b / 18; ct = b % 18;
    } else {
      const int b = bid - 1132;
      src = proj_w; W = 384; rt = b / 6; ct = b % 6;
    }
#pragma unroll
    for (int kk = 0; kk < 4; ++kk) {
      const int idx = tid + kk * 256;
      const int r = idx >> 4, c4 = idx & 15;
      const float4 v = *reinterpret_cast<const float4*>(src + (long)(rt * 64 + r) * W + ct * 64 + c4 * 4);
      tile[r][c4 * 4 + 0] = f2bf(v.x);
      tile[r][c4 * 4 + 1] = f2bf(v.y);
      tile[r][c4 * 4 + 2] = f2bf(v.z);
      tile[r][c4 * 4 + 3] = f2bf(v.w);
    }
    __syncthreads();
#pragma unroll
    for (int kk = 0; kk < 4; ++kk) {
      const int idx = tid + kk * 256;
      const int c = idx >> 4, r0 = (idx & 15) * 4;
      ushort4 o;
      o.x = tile[r0 + 0][c];
      o.y = tile[r0 + 1][c];
      o.z = tile[r0 + 2][c];
      o.w = tile[r0 + 3][c];
      const int col = ct * 64 + c, k = rt * 64 + r0;
      const int lane = ((k >> 3) & 3) * 16 + (col & 15);
      const int e = k & 7;  // 0 or 4
      long off;
      if (isqkv) {
        const int m = col / 384, colm = col - m * 384;
        const int h = colm >> 5, jn = (colm >> 4) & 1;
        off = (long)(((h * 3 + m) * 24) + (k >> 5) * 2 + jn) * 512 + lane * 8 + e;
        *reinterpret_cast<ushort4*>(qkvF + off) = o;
      } else {
        const int w = col / 96, colw = col - w * 96;
        const int jn = colw >> 4;
        off = (long)(w * 72 + (k >> 5) * 6 + jn) * 512 + lane * 8 + e;
        *reinterpret_cast<ushort4*>(projF + off) = o;
      }
    }
  } else if (bid == 1168) {
    if (tid < 12) scales[tid] = __expf(fminf(logit_scale[tid], 4.6051702f));
  } else {
    const int p = (bid - 1169) * 256 + tid;  // 0..4095
    const int t = rpb_idx[p];
#pragma unroll
    for (int h = 0; h < 12; ++h) bias[h * 4096 + p] = 16.f / (1.f + __expf(-rpb[t * 12 + h]));
  }
}

// ================= fused attention + projection (primary) =================
// LDS 48 KB; __launch_bounds__(256,2) -> empirical VGPR cap 128.
// Anti-spill v4 (R8 lesson: full unroll of the head loop let pre-RA LICM hoist all 3 heads'
// addresses/pointers -> ~200 MB chronic scratch despite ~110-reg phases). The head loop is
// now a REAL loop (#pragma unroll 1) — possible since R8's manual spill removed ow[hh].
// Per-head outputs go coalesced into the block's own out-slab; proj in 2 N-halves.
__global__ __launch_bounds__(256, 2) void attn_kernel(const u16* __restrict__ xF,
                                                      const float* __restrict__ mask,
                                                      const u16* __restrict__ qkvF,
                                                      const float* __restrict__ scales,
                                                      const float* __restrict__ bias,
                                                      const u16* __restrict__ projF,
                                                      const float* __restrict__ proj_b,
                                                      float* __restrict__ out) {
  __shared__ __align__(16) u16 sm[24576];  // 48 KB
  const int tid = threadIdx.x;
  const int wave = tid >> 6, lane = tid & 63;
  const int q16 = lane >> 4, c16 = lane & 15;
  const int widx = blockIdx.x, wm = widx & 63;
  u16* qs = sm + wave * 6144;   // [64][32] swz(row&3)
  u16* ks = qs + 2048;          // [64][32] swz(row&3)
  u16* ps = qs;                 // [64][64] swz(row&7), overlays qs+ks (safe: frags preloaded)
  u16* vst = qs + 4096;         // [32 d][64 tok] swz(d&7)
  const u16* xw = xF + (long)widx * 24576;
  unsigned* osp = reinterpret_cast<unsigned*>(out) + (long)widx * 24576;  // own-slab scratch
  const f32x4 fzero = {0.f, 0.f, 0.f, 0.f};

#pragma unroll 1
  for (int hh = 0; hh < 3; ++hh) {
    const int h = wave * 3 + hh;
    const float sc = scales[h];
    const u16* hb = qkvF + (long)h * 72 * 512;
    // ---- Pass QK: q,k = x_w @ Wq,Wk (64 accumulators) ----
    {
      f32x4 qa[4][2], ka[4][2];
#pragma unroll
      for (int i = 0; i < 4; ++i)
#pragma unroll
        for (int j = 0; j < 2; ++j) {
          qa[i][j] = fzero; ka[i][j] = fzero;
        }
#pragma unroll 1
      for (int t = 0; t < 12; ++t) {
        short8 af[4];
#pragma unroll
        for (int i = 0; i < 4; ++i)
          af[i] = *reinterpret_cast<const short8*>(xw + ((t * 4 + i) * 64 + lane) * 8);
#pragma unroll
        for (int jn = 0; jn < 2; ++jn) {
          const int fi = (2 * t + jn) * 512 + lane * 8;
          const short8 bq = *reinterpret_cast<const short8*>(hb + fi);
          const short8 bk = *reinterpret_cast<const short8*>(hb + 24 * 512 + fi);
#pragma unroll
          for (int i = 0; i < 4; ++i) {
            qa[i][jn] = MFMA16(af[i], bq, qa[i][jn]);
            ka[i][jn] = MFMA16(af[i], bk, ka[i][jn]);
          }
        }
      }
      // Phase B: normalize q (x scale) and k; stage qs/ks; kills qa/ka
      // C/D layout: col = lane&15, row = (lane>>4)*4 + reg
#pragma unroll
      for (int i = 0; i < 4; ++i) {
#pragma unroll
        for (int r = 0; r < 4; ++r) {
          const int row = 16 * i + 4 * q16 + r;
          float sq = qa[i][0][r] * qa[i][0][r] + qa[i][1][r] * qa[i][1][r];
          float sk = ka[i][0][r] * ka[i][0][r] + ka[i][1][r] * ka[i][1][r];
#pragma unroll
          for (int off = 1; off < 16; off <<= 1) {
            sq += __shfl_xor(sq, off);
            sk += __shfl_xor(sk, off);
          }
          const float rq = rsqrtf(fmaxf(sq, 1e-12f)) * sc;
          const float rk = rsqrtf(fmaxf(sk, 1e-12f));
          const int swq = (row & 3) << 3;
#pragma unroll
          for (int jn = 0; jn < 2; ++jn) {
            const int col = 16 * jn + c16;
            qs[(row * 32 + col) ^ swq] = f2bf(qa[i][jn][r] * rq);
            ks[(row * 32 + col) ^ swq] = f2bf(ka[i][jn][r] * rk);
          }
        }
      }
    }
    __builtin_amdgcn_sched_barrier(0);
    // ---- Pass V: v = x_w @ Wv (32 accumulators), stage v^T ----
    {
      f32x4 va[4][2];
#pragma unroll
      for (int i = 0; i < 4; ++i) {
        va[i][0] = fzero;
        va[i][1] = fzero;
      }
#pragma unroll 1
      for (int t = 0; t < 12; ++t) {
        short8 af[4];
#pragma unroll
        for (int i = 0; i < 4; ++i)
          af[i] = *reinterpret_cast<const short8*>(xw + ((t * 4 + i) * 64 + lane) * 8);
#pragma unroll
        for (int jn = 0; jn < 2; ++jn) {
          const short8 bv = *reinterpret_cast<const short8*>(hb + 48 * 512 + (2 * t + jn) * 512 + lane * 8);
#pragma unroll
          for (int i = 0; i < 4; ++i) va[i][jn] = MFMA16(af[i], bv, va[i][jn]);
        }
      }
#pragma unroll
      for (int i = 0; i < 4; ++i)
#pragma unroll
        for (int jn = 0; jn < 2; ++jn) {
          const int d = 16 * jn + c16;
          ushort4 vv;
          vv.x = f2bf(va[i][jn][0]);
          vv.y = f2bf(va[i][jn][1]);
          vv.z = f2bf(va[i][jn][2]);
          vv.w = f2bf(va[i][jn][3]);
          *reinterpret_cast<ushort4*>(vst + ((d * 64 + 16 * i + 4 * q16) ^ ((d & 7) << 3))) = vv;
        }
    }
    __builtin_amdgcn_sched_barrier(0);
    // ---- preload S-operand fragments (after this qs/ks dead -> ps overlay safe) ----
    short8 aq[4], bk4[4];
#pragma unroll
    for (int i = 0; i < 4; ++i) {
      const int row = c16 + 16 * i;
      aq[i] = *reinterpret_cast<const short8*>(qs + ((row * 32 + q16 * 8) ^ ((row & 3) << 3)));
      bk4[i] = *reinterpret_cast<const short8*>(ks + ((row * 32 + q16 * 8) ^ ((row & 3) << 3)));
    }
    __builtin_amdgcn_sched_barrier(0);
    // ---- chunked C/D/E: four independent 16-row groups ----
    const float* bh = bias + h * 4096;
    const float* mw = mask + (long)wm * 4096;
#pragma unroll
    for (int i = 0; i < 4; ++i) {
      // C: S rows = bias + mask, then QK^T
      f32x4 si[4];
#pragma unroll
      for (int j = 0; j < 4; ++j) {
        const int col = 16 * j + c16;
#pragma unroll
        for (int r = 0; r < 4; ++r) {
          const int row = 16 * i + 4 * q16 + r;
          si[j][r] = bh[row * 64 + col] + mw[row * 64 + col];
        }
      }
#pragma unroll
      for (int j = 0; j < 4; ++j) si[j] = MFMA16(aq[i], bk4[j], si[j]);
      // D: softmax over keys for these 16 rows, write ps rows
#pragma unroll
      for (int r = 0; r < 4; ++r) {
        float m = fmaxf(fmaxf(si[0][r], si[1][r]), fmaxf(si[2][r], si[3][r]));
#pragma unroll
        for (int off = 1; off < 16; off <<= 1) m = fmaxf(m, __shfl_xor(m, off));
        float e[4], s = 0.f;
#pragma unroll
        for (int j = 0; j < 4; ++j) {
          e[j] = __expf(si[j][r] - m);
          s += e[j];
        }
#pragma unroll
        for (int off = 1; off < 16; off <<= 1) s += __shfl_xor(s, off);
        const float inv = 1.f / s;
        const int row = 16 * i + 4 * q16 + r;
        const int sw = (row & 7) << 3;
#pragma unroll
        for (int j = 0; j < 4; ++j) ps[(row * 64 + 16 * j + c16) ^ sw] = f2bf(e[j] * inv);
      }
      // E: O rows for this group = P rows @ V
      f32x4 oi[2];
      oi[0] = fzero;
      oi[1] = fzero;
      const int rowp = c16 + 16 * i;
#pragma unroll
      for (int kt = 0; kt < 2; ++kt) {
        const short8 api = *reinterpret_cast<const short8*>(
            ps + ((rowp * 64 + kt * 32 + q16 * 8) ^ ((rowp & 7) << 3)));
#pragma unroll
        for (int jn = 0; jn < 2; ++jn) {
          const int d = 16 * jn + c16;
          const short8 bvf = *reinterpret_cast<const short8*>(
              vst + ((d * 64 + kt * 32 + q16 * 8) ^ ((d & 7) << 3)));
          oi[jn] = MFMA16(api, bvf, oi[jn]);
        }
      }
      // manual coalesced spill of this row group's packed bf16 output (own out-slab)
#pragma unroll
      for (int jn = 0; jn < 2; ++jn) {
        const unsigned w0 = (unsigned)f2bf(oi[jn][0]) | ((unsigned)f2bf(oi[jn][1]) << 16);
        const unsigned w1 = (unsigned)f2bf(oi[jn][2]) | ((unsigned)f2bf(oi[jn][3]) << 16);
        osp[(hh * 16 + i * 4 + jn * 2 + 0) * 256 + tid] = w0;
        osp[(hh * 16 + i * 4 + jn * 2 + 1) * 256 + tid] = w1;
      }
      __builtin_amdgcn_sched_barrier(0);  // pin chunk boundary (no cross-chunk hoisting)
    }
  }
  __syncthreads();  // all waves done with wave scratch
  // ---- stage activation tile [64][384] bf16 (swizzled), reloading the manual spill ----
#pragma unroll 1
  for (int hh = 0; hh < 3; ++hh) {
    const int cb = (wave * 3 + hh) * 32;
#pragma unroll
    for (int i = 0; i < 4; ++i)
#pragma unroll
      for (int jn = 0; jn < 2; ++jn)
#pragma unroll
        for (int p = 0; p < 2; ++p) {
          const unsigned w = osp[(hh * 16 + i * 4 + jn * 2 + p) * 256 + tid];
          const int col = cb + 16 * jn + c16;
          const int r0 = 16 * i + 4 * q16 + 2 * p;
          sm[(r0 * 384 + col) ^ ((r0 & 7) << 3)] = (u16)(w & 0xffffu);
          sm[((r0 + 1) * 384 + col) ^ (((r0 + 1) & 7) << 3)] = (u16)(w >> 16);
        }
  }
  __syncthreads();  // spill fully consumed into LDS -> safe to overwrite out below
  // ---- fused projection in 2 N-halves: out = act @ projF + b  (M=64, N=384, K=384) ----
  const u16* pb = projF + (long)wave * 72 * 512;
  float* ob = out + (long)widx * 24576;
#pragma unroll 1
  for (int half = 0; half < 2; ++half) {
    f32x4 pacc[4][3];
#pragma unroll
    for (int i = 0; i < 4; ++i)
#pragma unroll
      for (int jn = 0; jn < 3; ++jn) pacc[i][jn] = fzero;
#pragma unroll 1
    for (int t = 0; t < 12; ++t) {
      const int k0 = t * 32 + q16 * 8;
      short8 af[4];
#pragma unroll
      for (int i = 0; i < 4; ++i) {
        const int row = c16 + 16 * i;
        af[i] = *reinterpret_cast<const short8*>(sm + ((row * 384 + k0) ^ ((row & 7) << 3)));
      }
#pragma unroll
      for (int jn = 0; jn < 3; ++jn) {
        const short8 bw = *reinterpret_cast<const short8*>(pb + (t * 6 + half * 3 + jn) * 512 + lane * 8);
#pragma unroll
        for (int i = 0; i < 4; ++i) pacc[i][jn] = MFMA16(af[i], bw, pacc[i][jn]);
      }
    }
#pragma unroll
    for (int jn = 0; jn < 3; ++jn) {
      const int n = wave * 96 + (half * 3 + jn) * 16 + c16;
      const float bv = proj_b[n];
#pragma unroll
      for (int i = 0; i < 4; ++i)
#pragma unroll
        for (int r = 0; r < 4; ++r)
          ob[(long)(16 * i + 4 * q16 + r) * 384 + n] = pacc[i][jn][r] + bv;
    }
  }
}

// ================= fallback (no xF workspace): x staged via 96 KB LDS =================
__global__ __launch_bounds__(256, 1) void attn_fb(const float* __restrict__ x,
                                                  const float* __restrict__ mask,
                                                  const u16* __restrict__ qkvF,
                                                  const float* __restrict__ scales,
                                                  const float* __restrict__ bias,
                                                  const u16* __restrict__ projF,
                                                  const float* __restrict__ proj_b,
                                                  float* __restrict__ out) {
  __shared__ __align__(16) u16 sm[49152];  // 96 KB
  const int tid = threadIdx.x;
  const int wave = tid >> 6, lane = tid & 63;
  const int q16 = lane >> 4, c16 = lane & 15;
  const int widx = blockIdx.x, wm = widx & 63;
  u16* qs = sm + wave * 6144;
  u16* ks = qs + 2048;
  u16* ps = qs;
  u16* vst = qs + 4096;
  u16* xs = sm + 24576;
  const f32x4 fzero = {0.f, 0.f, 0.f, 0.f};
  {
    const float4* x4 = reinterpret_cast<const float4*>(x + (long)widx * 24576);
#pragma unroll
    for (int it = 0; it < 12; ++it) {
      const int c = it * 256 + tid;
      const float4 a = x4[2 * c];
      const float4 b = x4[2 * c + 1];
      short8 v;
      v[0] = (short)f2bf(a.x); v[1] = (short)f2bf(a.y); v[2] = (short)f2bf(a.z); v[3] = (short)f2bf(a.w);
      v[4] = (short)f2bf(b.x); v[5] = (short)f2bf(b.y); v[6] = (short)f2bf(b.z); v[7] = (short)f2bf(b.w);
      const int row = c / 48;
      *reinterpret_cast<short8*>(xs + ((c * 8) ^ ((row & 7) << 3))) = v;
    }
  }
  __syncthreads();
  unsigned ow[3][4][2][2];
#pragma unroll
  for (int hh = 0; hh < 3; ++hh) {
    const int h = wave * 3 + hh;
    const float sc = scales[h];
    const u16* hb = qkvF + (long)h * 72 * 512;
    f32x4 qa[4][2], ka[4][2], va[4][2];
#pragma unroll
    for (int i = 0; i < 4; ++i)
#pragma unroll
      for (int j = 0; j < 2; ++j) {
        qa[i][j] = fzero; ka[i][j] = fzero; va[i][j] = fzero;
      }
#pragma unroll 1
    for (int t = 0; t < 12; ++t) {
      const int k0 = t * 32 + q16 * 8;
      short8 af[4];
#pragma unroll
      for (int i = 0; i < 4; ++i) {
        const int row = c16 + 16 * i;
        af[i] = *reinterpret_cast<const short8*>(xs + ((row * 384 + k0) ^ ((row & 7) << 3)));
      }
#pragma unroll
      for (int jn = 0; jn < 2; ++jn) {
        const int fi = (2 * t + jn) * 512 + lane * 8;
        const short8 bq = *reinterpret_cast<const short8*>(hb + fi);
        const short8 bk = *reinterpret_cast<const short8*>(hb + 24 * 512 + fi);
        const short8 bv = *reinterpret_cast<const short8*>(hb + 48 * 512 + fi);
#pragma unroll
        for (int i = 0; i < 4; ++i) {
          qa[i][jn] = MFMA16(af[i], bq, qa[i][jn]);
          ka[i][jn] = MFMA16(af[i], bk, ka[i][jn]);
          va[i][jn] = MFMA16(af[i], bv, va[i][jn]);
        }
      }
    }
#pragma unroll
    for (int i = 0; i < 4; ++i) {
#pragma unroll
      for (int r = 0; r < 4; ++r) {
        const int row = 16 * i + 4 * q16 + r;
        float sq = qa[i][0][r] * qa[i][0][r] + qa[i][1][r] * qa[i][1][r];
        float sk = ka[i][0][r] * ka[i][0][r] + ka[i][1][r] * ka[i][1][r];
#pragma unroll
        for (int off = 1; off < 16; off <<= 1) {
          sq += __shfl_xor(sq, off);
          sk += __shfl_xor(sk, off);
        }
        const float rq = rsqrtf(fmaxf(sq, 1e-12f)) * sc;
        const float rk = rsqrtf(fmaxf(sk, 1e-12f));
        const int swq = (row & 3) << 3;
#pragma unroll
        for (int jn = 0; jn < 2; ++jn) {
          const int col = 16 * jn + c16;
          qs[(row * 32 + col) ^ swq] = f2bf(qa[i][jn][r] * rq);
          ks[(row * 32 + col) ^ swq] = f2bf(ka[i][jn][r] * rk);
          vst[(col * 64 + row) ^ ((col & 7) << 3)] = f2bf(va[i][jn][r]);
        }
      }
    }
    f32x4 sacc[4][4];
    {
      const float* bh = bias + h * 4096;
      const float* mw = mask + (long)wm * 4096;
#pragma unroll
      for (int i = 0; i < 4; ++i)
#pragma unroll
        for (int j = 0; j < 4; ++j) {
          const int col = 16 * j + c16;
#pragma unroll
          for (int r = 0; r < 4; ++r) {
            const int row = 16 * i + 4 * q16 + r;
            sacc[i][j][r] = bh[row * 64 + col] + mw[row * 64 + col];
          }
        }
    }
    short8 aq[4], bk4[4];
#pragma unroll
    for (int i = 0; i < 4; ++i) {
      const int row = c16 + 16 * i;
      aq[i] = *reinterpret_cast<const short8*>(qs + ((row * 32 + q16 * 8) ^ ((row & 3) << 3)));
      bk4[i] = *reinterpret_cast<const short8*>(ks + ((row * 32 + q16 * 8) ^ ((row & 3) << 3)));
    }
#pragma unroll
    for (int i = 0; i < 4; ++i)
#pragma unroll
      for (int j = 0; j < 4; ++j) sacc[i][j] = MFMA16(aq[i], bk4[j], sacc[i][j]);
#pragma unroll
    for (int i = 0; i < 4; ++i) {
#pragma unroll
      for (int r = 0; r < 4; ++r) {
        float m = fmaxf(fmaxf(sacc[i][0][r], sacc[i][1][r]), fmaxf(sacc[i][2][r], sacc[i][3][r]));
#pragma unroll
        for (int off = 1; off < 16; off <<= 1) m = fmaxf(m, __shfl_xor(m, off));
        float e[4], s = 0.f;
#pragma unroll
        for (int j = 0; j < 4; ++j) {
          e[j] = __expf(sacc[i][j][r] - m);
          s += e[j];
        }
#pragma unroll
        for (int off = 1; off < 16; off <<= 1) s += __shfl_xor(s, off);
        const float inv = 1.f / s;
        const int row = 16 * i + 4 * q16 + r;
        const int sw = (row & 7) << 3;
#pragma unroll
        for (int j = 0; j < 4; ++j) ps[(row * 64 + 16 * j + c16) ^ sw] = f2bf(e[j] * inv);
      }
    }
    f32x4 oa[4][2];
#pragma unroll
    for (int i = 0; i < 4; ++i) {
      oa[i][0] = fzero;
      oa[i][1] = fzero;
    }
#pragma unroll
    for (int kt = 0; kt < 2; ++kt) {
      short8 ap[4], bv2[2];
#pragma unroll
      for (int i = 0; i < 4; ++i) {
        const int row = c16 + 16 * i;
        ap[i] = *reinterpret_cast<const short8*>(ps + ((row * 64 + kt * 32 + q16 * 8) ^ ((row & 7) << 3)));
      }
#pragma unroll
      for (int jn = 0; jn < 2; ++jn) {
        const int d = 16 * jn + c16;
        bv2[jn] = *reinterpret_cast<const short8*>(vst + ((d * 64 + kt * 32 + q16 * 8) ^ ((d & 7) << 3)));
      }
#pragma unroll
      for (int i = 0; i < 4; ++i)
#pragma unroll
        for (int jn = 0; jn < 2; ++jn) oa[i][jn] = MFMA16(ap[i], bv2[jn], oa[i][jn]);
    }
#pragma unroll
    for (int i = 0; i < 4; ++i)
#pragma unroll
      for (int jn = 0; jn < 2; ++jn) {
        ow[hh][i][jn][0] = (unsigned)f2bf(oa[i][jn][0]) | ((unsigned)f2bf(oa[i][jn][1]) << 16);
        ow[hh][i][jn][1] = (unsigned)f2bf(oa[i][jn][2]) | ((unsigned)f2bf(oa[i][jn][3]) << 16);
      }
  }
  __syncthreads();
#pragma unroll
  for (int hh = 0; hh < 3; ++hh) {
    const int cb = (wave * 3 + hh) * 32;
#pragma unroll
    for (int i = 0; i < 4; ++i)
#pragma unroll
      for (int jn = 0; jn < 2; ++jn)
#pragma unroll
        for (int p = 0; p < 2; ++p) {
          const unsigned w = ow[hh][i][jn][p];
          const int col = cb + 16 * jn + c16;
          const int r0 = 16 * i + 4 * q16 + 2 * p;
          xs[(r0 * 384 + col) ^ ((r0 & 7) << 3)] = (u16)(w & 0xffffu);
          xs[((r0 + 1) * 384 + col) ^ (((r0 + 1) & 7) << 3)] = (u16)(w >> 16);
        }
  }
  __syncthreads();
  const u16* pb = projF + (long)wave * 72 * 512;
  f32x4 pacc[4][6];
#pragma unroll
  for (int i = 0; i < 4; ++i)
#pragma unroll
    for (int jn = 0; jn < 6; ++jn) pacc[i][jn] = fzero;
#pragma unroll 1
  for (int t = 0; t < 12; ++t) {
    const int k0 = t * 32 + q16 * 8;
    short8 af[4];
#pragma unroll
    for (int i = 0; i < 4; ++i) {
      const int row = c16 + 16 * i;
      af[i] = *reinterpret_cast<const short8*>(xs + ((row * 384 + k0) ^ ((row & 7) << 3)));
    }
#pragma unroll
    for (int jn = 0; jn < 6; ++jn) {
      const short8 bw = *reinterpret_cast<const short8*>(pb + (t * 6 + jn) * 512 + lane * 8);
#pragma unroll
      for (int i = 0; i < 4; ++i) pacc[i][jn] = MFMA16(af[i], bw, pacc[i][jn]);
    }
  }
  float* ob = out + (long)widx * 24576;
#pragma unroll
  for (int jn = 0; jn < 6; ++jn) {
    const int n = wave * 96 + 16 * jn + c16;
    const float bv = proj_b[n];
#pragma unroll
    for (int i = 0; i < 4; ++i)
#pragma unroll
      for (int r = 0; r < 4; ++r)
        ob[(long)(16 * i + 4 * q16 + r) * 384 + n] = pacc[i][jn][r] + bv;
  }
}

extern "C" void kernel_launch(void* const* d_in, const int* in_sizes, int n_in, void* d_out,
                              int out_size, void* d_ws, size_t ws_size, hipStream_t stream) {
  const float* x = (const float*)d_in[0];
  const float* mask = (const float*)d_in[1];
  const float* qkv_w = (const float*)d_in[2];
  const float* proj_w = (const float*)d_in[3];
  const float* proj_b = (const float*)d_in[4];
  const float* cpb_w1 = (const float*)d_in[5];
  const float* cpb_b1 = (const float*)d_in[6];
  const float* cpb_w2 = (const float*)d_in[7];
  const float* cpb_b2 = (const float*)d_in[8];
  const float* logit_scale = (const float*)d_in[9];
  const float* rpb_table = (const float*)d_in[10];
  const int* rpb_idx = (const int*)d_in[11];

  char* ws = (char*)d_ws;
  float* bias = (float*)(ws + OFF_BIAS);
  float* scales = (float*)(ws + OFF_SCALES);
  float* rpb = (float*)(ws + OFF_RPB);
  u16* qkvF = (u16*)(ws + OFF_QKVF);
  u16* projF = (u16*)(ws + OFF_PROJF);
  u16* xF = (u16*)(ws + OFF_XF);

  prep_cpb<<<225, 256, 0, stream>>>(rpb_table, cpb_w1, cpb_b1, cpb_w2, cpb_b2, rpb);
  const bool big = ws_size >= WS_NEED;
  if (big) {
    prep_all<<<1185, 256, 0, stream>>>(x, qkv_w, proj_w, logit_scale, rpb, rpb_idx,
                                       xF, qkvF, projF, scales, bias, 0);
    attn_kernel<<<1024, 256, 0, stream>>>(xF, mask, qkvF, scales, bias, projF, proj_b,
                                          (float*)d_out);
  } else {
    prep_all<<<161, 256, 0, stream>>>(x, qkv_w, proj_w, logit_scale, rpb, rpb_idx,
                                      xF, qkvF, projF, scales, bias, 1024);
    attn_fb<<<1024, 256, 0, stream>>>(x, mask, qkvF, scales, bias, projF, proj_b, (float*)d_out);
  }
}

// Round 10
// 358.792 us; speedup vs baseline: 1.4103x; 1.4103x over previous
//
#include <hip/hip_runtime.h>

typedef unsigned short u16;
typedef __attribute__((ext_vector_type(8))) short short8;
typedef __attribute__((ext_vector_type(4))) float f32x4;

#define MFMA16(a, b, c) __builtin_amdgcn_mfma_f32_16x16x32_bf16((a), (b), (c), 0, 0, 0)

// ---- workspace layout (bytes) ----
#define OFF_BIAS 0            // fp32 [12][64][64]      = 196608
#define OFF_SCALES 196608     // fp32 [12]              (64 B slot)
#define OFF_RPB 196672        // fp32 [225][12]         = 10800 (slot to 207616)
#define OFF_QKVF 207616       // bf16 frag-ordered qkv weights = 884736
#define OFF_PROJF 1092352     // bf16 frag-ordered proj weights = 294912 (end 1387264)
#define OFF_XF 1387264        // bf16 fragment-ordered x: 1024 * 24576 u16 = 50331648
#define WS_NEED (1387264UL + 50331648UL)

// qkvF layout: frag(h,m,t,jn) at ((h*3+m)*24 + 2*t + jn)*512 + lane*8   (u16 units)
// projF layout: frag(w,t,jn)  at (w*72 + t*6 + jn)*512 + lane*8
// xF layout:    frag(t,i)     at ((t*4+i)*64 + lane)*8  within window slab of 24576
// actF layout (fp32, in d_out): frag f at widx*24576 + (f*64 + lane)*8  (8 floats/lane)

__device__ __forceinline__ u16 f2bf(float f) {
  unsigned x = __float_as_uint(f);
  return (u16)((x + 0x7fffu + ((x >> 16) & 1u)) >> 16);  // RNE, finite values only
}

// ================= prep: CPB MLP, one block per table entry (225 blocks) =================
__global__ __launch_bounds__(256) void prep_cpb(const float* __restrict__ tab, const float* __restrict__ w1,
                                                const float* __restrict__ b1, const float* __restrict__ w2,
                                                const float* __restrict__ b2, float* __restrict__ rpb) {
  const int t = blockIdx.x;   // 0..224
  const int tid = threadIdx.x;
  const float t0 = tab[2 * t], t1 = tab[2 * t + 1];
  float acc[12];
#pragma unroll
  for (int h = 0; h < 12; ++h) acc[h] = 0.f;
  for (int j = tid; j < 512; j += 256) {
    const float hv = fmaxf(t0 * w1[j] + t1 * w1[512 + j] + b1[j], 0.f);
#pragma unroll
    for (int h = 0; h < 12; ++h) acc[h] += hv * w2[j * 12 + h];
  }
#pragma unroll
  for (int h = 0; h < 12; ++h)
#pragma unroll
    for (int off = 1; off < 64; off <<= 1) acc[h] += __shfl_xor(acc[h], off);
  __shared__ float red[4][12];
  const int wave = tid >> 6;
  if ((tid & 63) == 0) {
#pragma unroll
    for (int h = 0; h < 12; ++h) red[wave][h] = acc[h];
  }
  __syncthreads();
  if (tid < 12) rpb[t * 12 + tid] = red[0][tid] + red[1][tid] + red[2][tid] + red[3][tid] + b2[tid];
}

// ================= unified prep =================
__global__ __launch_bounds__(256) void prep_all(const float* __restrict__ x,
                                                const float* __restrict__ qkv_w,
                                                const float* __restrict__ proj_w,
                                                const float* __restrict__ logit_scale,
                                                const float* __restrict__ rpb,
                                                const int* __restrict__ rpb_idx,
                                                u16* __restrict__ xF, u16* __restrict__ qkvF,
                                                u16* __restrict__ projF, float* __restrict__ scales,
                                                float* __restrict__ bias, int bid0) {
  __shared__ __align__(16) u16 sm[24576];  // 48 KB, unioned per branch
  const int bid = blockIdx.x + bid0;
  const int tid = threadIdx.x;
  if (bid < 1024) {
    // ---- stage x window (fp32 -> bf16, swizzled, coalesced) ----
    const float4* x4 = reinterpret_cast<const float4*>(x + (long)bid * 24576);
#pragma unroll
    for (int it = 0; it < 12; ++it) {
      const int c = it * 256 + tid;  // 8-u16 chunk id, 0..3071
      const float4 a = x4[2 * c];
      const float4 b = x4[2 * c + 1];
      short8 v;
      v[0] = (short)f2bf(a.x); v[1] = (short)f2bf(a.y); v[2] = (short)f2bf(a.z); v[3] = (short)f2bf(a.w);
      v[4] = (short)f2bf(b.x); v[5] = (short)f2bf(b.y); v[6] = (short)f2bf(b.z); v[7] = (short)f2bf(b.w);
      const int row = c / 48;
      *reinterpret_cast<short8*>(sm + ((c * 8) ^ ((row & 7) << 3))) = v;
    }
    __syncthreads();
    // ---- emit fragment-ordered (coalesced writes) ----
    u16* dst = xF + (long)bid * 24576;
#pragma unroll
    for (int it = 0; it < 12; ++it) {
      const int slot = it * 256 + tid;           // 0..3071 = 48 frags x 64 lanes
      const int f = slot >> 6, l = slot & 63;
      const int row = 16 * (f & 3) + (l & 15);
      const int k0 = (f >> 2) * 32 + (l >> 4) * 8;
      const short8 v = *reinterpret_cast<const short8*>(sm + ((row * 384 + k0) ^ ((row & 7) << 3)));
      *reinterpret_cast<short8*>(dst + slot * 8) = v;
    }
  } else if (bid < 1168) {
    u16(*tile)[66] = reinterpret_cast<u16(*)[66]>(sm);  // pad 66: column reads 2-way (free)
    const float* src;
    int W, rt, ct;
    const bool isqkv = bid < 1132;
    if (isqkv) {
      const int b = bid - 1024;
      src = qkv_w; W = 1152; rt = b / 18; ct = b % 18;
    } else {
      const int b = bid - 1132;
      src = proj_w; W = 384; rt = b / 6; ct = b % 6;
    }
#pragma unroll
    for (int kk = 0; kk < 4; ++kk) {
      const int idx = tid + kk * 256;
      const int r = idx >> 4, c4 = idx & 15;
      const float4 v = *reinterpret_cast<const float4*>(src + (long)(rt * 64 + r) * W + ct * 64 + c4 * 4);
      tile[r][c4 * 4 + 0] = f2bf(v.x);
      tile[r][c4 * 4 + 1] = f2bf(v.y);
      tile[r][c4 * 4 + 2] = f2bf(v.z);
      tile[r][c4 * 4 + 3] = f2bf(v.w);
    }
    __syncthreads();
#pragma unroll
    for (int kk = 0; kk < 4; ++kk) {
      const int idx = tid + kk * 256;
      const int c = idx >> 4, r0 = (idx & 15) * 4;
      ushort4 o;
      o.x = tile[r0 + 0][c];
      o.y = tile[r0 + 1][c];
      o.z = tile[r0 + 2][c];
      o.w = tile[r0 + 3][c];
      const int col = ct * 64 + c, k = rt * 64 + r0;
      const int lane = ((k >> 3) & 3) * 16 + (col & 15);
      const int e = k & 7;  // 0 or 4
      long off;
      if (isqkv) {
        const int m = col / 384, colm = col - m * 384;
        const int h = colm >> 5, jn = (colm >> 4) & 1;
        off = (long)(((h * 3 + m) * 24) + (k >> 5) * 2 + jn) * 512 + lane * 8 + e;
        *reinterpret_cast<ushort4*>(qkvF + off) = o;
      } else {
        const int w = col / 96, colw = col - w * 96;
        const int jn = colw >> 4;
        off = (long)(w * 72 + (k >> 5) * 6 + jn) * 512 + lane * 8 + e;
        *reinterpret_cast<ushort4*>(projF + off) = o;
      }
    }
  } else if (bid == 1168) {
    if (tid < 12) scales[tid] = __expf(fminf(logit_scale[tid], 4.6051702f));
  } else {
    const int p = (bid - 1169) * 256 + tid;  // 0..4095
    const int t = rpb_idx[p];
#pragma unroll
    for (int h = 0; h < 12; ++h) bias[h * 4096 + p] = 16.f / (1.f + __expf(-rpb[t * 12 + h]));
  }
}

// ================= attention, ONE HEAD PER WAVE (primary) =================
// grid 3072 = 1024 windows x 3 head-groups; wave w of block handles head (bid%3)*4+w.
// Serial chain per wave is 1/3 of the old 3-head loop. All LDS wave-private, NO barriers.
// Output: fp32 fragment-ordered activations into d_out (self-slab only; proj2 consumes).
// Peak live regs <= ~108 under the known (256,2)->128 cap -> zero scratch expected.
__global__ __launch_bounds__(256, 2) void attn1(const u16* __restrict__ xF,
                                                const float* __restrict__ mask,
                                                const u16* __restrict__ qkvF,
                                                const float* __restrict__ scales,
                                                const float* __restrict__ bias,
                                                float* __restrict__ actF) {
  __shared__ __align__(16) u16 sm[24576];  // 48 KB = 4 waves x 12 KB private
  const int tid = threadIdx.x;
  const int wave = tid >> 6, lane = tid & 63;
  const int q16 = lane >> 4, c16 = lane & 15;
  const int bid = blockIdx.x;
  const int widx = bid / 3, hgrp = bid - widx * 3;
  const int wm = widx & 63;
  const int h = hgrp * 4 + wave;
  u16* qs = sm + wave * 6144;   // [64][32] swz(row&3)
  u16* ks = qs + 2048;          // [64][32] swz(row&3)
  u16* ps = qs;                 // [64][64] swz(row&7), overlays qs+ks (safe: frags preloaded)
  u16* vst = qs + 4096;         // [32 d][64 tok] swz(d&7)
  const u16* xw = xF + (long)widx * 24576;
  const u16* hb = qkvF + (long)h * 72 * 512;
  const float sc = scales[h];
  const f32x4 fzero = {0.f, 0.f, 0.f, 0.f};

  // ---- Pass QK: q,k = x_w @ Wq,Wk (64 accumulators) ----
  {
    f32x4 qa[4][2], ka[4][2];
#pragma unroll
    for (int i = 0; i < 4; ++i)
#pragma unroll
      for (int j = 0; j < 2; ++j) {
        qa[i][j] = fzero; ka[i][j] = fzero;
      }
#pragma unroll 1
    for (int t = 0; t < 12; ++t) {
      short8 af[4];
#pragma unroll
      for (int i = 0; i < 4; ++i)
        af[i] = *reinterpret_cast<const short8*>(xw + ((t * 4 + i) * 64 + lane) * 8);
#pragma unroll
      for (int jn = 0; jn < 2; ++jn) {
        const int fi = (2 * t + jn) * 512 + lane * 8;
        const short8 bq = *reinterpret_cast<const short8*>(hb + fi);
        const short8 bk = *reinterpret_cast<const short8*>(hb + 24 * 512 + fi);
#pragma unroll
        for (int i = 0; i < 4; ++i) {
          qa[i][jn] = MFMA16(af[i], bq, qa[i][jn]);
          ka[i][jn] = MFMA16(af[i], bk, ka[i][jn]);
        }
      }
    }
    // normalize q (x scale) and k; stage qs/ks; kills qa/ka
    // C/D layout: col = lane&15, row = (lane>>4)*4 + reg
#pragma unroll
    for (int i = 0; i < 4; ++i) {
#pragma unroll
      for (int r = 0; r < 4; ++r) {
        const int row = 16 * i + 4 * q16 + r;
        float sq = qa[i][0][r] * qa[i][0][r] + qa[i][1][r] * qa[i][1][r];
        float sk = ka[i][0][r] * ka[i][0][r] + ka[i][1][r] * ka[i][1][r];
#pragma unroll
        for (int off = 1; off < 16; off <<= 1) {
          sq += __shfl_xor(sq, off);
          sk += __shfl_xor(sk, off);
        }
        const float rq = rsqrtf(fmaxf(sq, 1e-12f)) * sc;
        const float rk = rsqrtf(fmaxf(sk, 1e-12f));
        const int swq = (row & 3) << 3;
#pragma unroll
        for (int jn = 0; jn < 2; ++jn) {
          const int col = 16 * jn + c16;
          qs[(row * 32 + col) ^ swq] = f2bf(qa[i][jn][r] * rq);
          ks[(row * 32 + col) ^ swq] = f2bf(ka[i][jn][r] * rk);
        }
      }
    }
  }
  __builtin_amdgcn_sched_barrier(0);
  // ---- Pass V: v = x_w @ Wv (32 accumulators), stage v^T ----
  {
    f32x4 va[4][2];
#pragma unroll
    for (int i = 0; i < 4; ++i) {
      va[i][0] = fzero;
      va[i][1] = fzero;
    }
#pragma unroll 1
    for (int t = 0; t < 12; ++t) {
      short8 af[4];
#pragma unroll
      for (int i = 0; i < 4; ++i)
        af[i] = *reinterpret_cast<const short8*>(xw + ((t * 4 + i) * 64 + lane) * 8);
#pragma unroll
      for (int jn = 0; jn < 2; ++jn) {
        const short8 bv = *reinterpret_cast<const short8*>(hb + 48 * 512 + (2 * t + jn) * 512 + lane * 8);
#pragma unroll
        for (int i = 0; i < 4; ++i) va[i][jn] = MFMA16(af[i], bv, va[i][jn]);
      }
    }
#pragma unroll
    for (int i = 0; i < 4; ++i)
#pragma unroll
      for (int jn = 0; jn < 2; ++jn) {
        const int d = 16 * jn + c16;
        ushort4 vv;
        vv.x = f2bf(va[i][jn][0]);
        vv.y = f2bf(va[i][jn][1]);
        vv.z = f2bf(va[i][jn][2]);
        vv.w = f2bf(va[i][jn][3]);
        *reinterpret_cast<ushort4*>(vst + ((d * 64 + 16 * i + 4 * q16) ^ ((d & 7) << 3))) = vv;
      }
  }
  __builtin_amdgcn_sched_barrier(0);
  // ---- preload S-operand fragments (after this qs/ks dead -> ps overlay safe) ----
  short8 aq[4], bk4[4];
#pragma unroll
  for (int i = 0; i < 4; ++i) {
    const int row = c16 + 16 * i;
    aq[i] = *reinterpret_cast<const short8*>(qs + ((row * 32 + q16 * 8) ^ ((row & 3) << 3)));
    bk4[i] = *reinterpret_cast<const short8*>(ks + ((row * 32 + q16 * 8) ^ ((row & 3) << 3)));
  }
  __builtin_amdgcn_sched_barrier(0);
  // ---- chunked C/D/E: four independent 16-row groups; O kept in 32 regs ----
  const float* bh = bias + h * 4096;
  const float* mw = mask + (long)wm * 4096;
  f32x4 oa[4][2];
#pragma unroll
  for (int i = 0; i < 4; ++i) {
    // C: S rows = bias + mask, then QK^T
    f32x4 si[4];
#pragma unroll
    for (int j = 0; j < 4; ++j) {
      const int col = 16 * j + c16;
#pragma unroll
      for (int r = 0; r < 4; ++r) {
        const int row = 16 * i + 4 * q16 + r;
        si[j][r] = bh[row * 64 + col] + mw[row * 64 + col];
      }
    }
#pragma unroll
    for (int j = 0; j < 4; ++j) si[j] = MFMA16(aq[i], bk4[j], si[j]);
    // D: softmax over keys for these 16 rows, write ps rows
#pragma unroll
    for (int r = 0; r < 4; ++r) {
      float m = fmaxf(fmaxf(si[0][r], si[1][r]), fmaxf(si[2][r], si[3][r]));
#pragma unroll
      for (int off = 1; off < 16; off <<= 1) m = fmaxf(m, __shfl_xor(m, off));
      float e[4], s = 0.f;
#pragma unroll
      for (int j = 0; j < 4; ++j) {
        e[j] = __expf(si[j][r] - m);
        s += e[j];
      }
#pragma unroll
      for (int off = 1; off < 16; off <<= 1) s += __shfl_xor(s, off);
      const float inv = 1.f / s;
      const int row = 16 * i + 4 * q16 + r;
      const int sw = (row & 7) << 3;
#pragma unroll
      for (int j = 0; j < 4; ++j) ps[(row * 64 + 16 * j + c16) ^ sw] = f2bf(e[j] * inv);
    }
    // E: O rows for this group = P rows @ V
    oa[i][0] = fzero;
    oa[i][1] = fzero;
    const int rowp = c16 + 16 * i;
#pragma unroll
    for (int kt = 0; kt < 2; ++kt) {
      const short8 api = *reinterpret_cast<const short8*>(
          ps + ((rowp * 64 + kt * 32 + q16 * 8) ^ ((rowp & 7) << 3)));
#pragma unroll
      for (int jn = 0; jn < 2; ++jn) {
        const int d = 16 * jn + c16;
        const short8 bvf = *reinterpret_cast<const short8*>(
            vst + ((d * 64 + kt * 32 + q16 * 8) ^ ((d & 7) << 3)));
        oa[i][jn] = MFMA16(api, bvf, oa[i][jn]);
      }
    }
    __builtin_amdgcn_sched_barrier(0);  // pin chunk boundary
  }
  // ---- transpose O via wave-private LDS (ps area, now dead) and emit frag-ordered fp32 ----
  float* psf = reinterpret_cast<float*>(qs);  // 8 KB fp32 [64][32] swz(row&3)
#pragma unroll
  for (int i = 0; i < 4; ++i)
#pragma unroll
    for (int jn = 0; jn < 2; ++jn)
#pragma unroll
      for (int r = 0; r < 4; ++r) {
        const int row = 16 * i + 4 * q16 + r;
        psf[(row * 32 + 16 * jn + c16) ^ ((row & 3) << 3)] = oa[i][jn][r];
      }
  float* dstw = actF + (long)widx * 24576;
#pragma unroll
  for (int i = 0; i < 4; ++i) {
    const int row = 16 * i + (lane & 15);
    const int idx = ((row * 32 + (lane >> 4) * 8) ^ ((row & 3) << 3));
    const float4 a = *reinterpret_cast<const float4*>(psf + idx);
    const float4 b = *reinterpret_cast<const float4*>(psf + idx + 4);
    float* d = dstw + ((h * 4 + i) * 64 + lane) * 8;
    *reinterpret_cast<float4*>(d) = a;
    *reinterpret_cast<float4*>(d + 4) = b;
  }
}

// ================= projection: out = act @ projF + b, in place on d_out =================
// Block = window. Stage own fp32 act slab -> bf16 LDS (frag-contiguous), barrier, GEMM in
// 2 N-halves (pacc[4][3]=48 regs), overwrite the same slab. Reads precede writes -> safe.
__global__ __launch_bounds__(256, 2) void proj2(const float* __restrict__ actF,
                                                const u16* __restrict__ projF,
                                                const float* __restrict__ proj_b,
                                                float* __restrict__ out) {
  __shared__ __align__(16) u16 sm[24576];  // 48 KB, frag-contiguous bf16 act
  const int tid = threadIdx.x;
  const int wave = tid >> 6, lane = tid & 63;
  const int q16 = lane >> 4, c16 = lane & 15;
  const int widx = blockIdx.x;
  const f32x4 fzero = {0.f, 0.f, 0.f, 0.f};
  {
    const float4* a4 = reinterpret_cast<const float4*>(actF + (long)widx * 24576);
#pragma unroll
    for (int it = 0; it < 12; ++it) {
      const int s = it * 256 + tid;  // short8 slot 0..3071
      const float4 a = a4[2 * s];
      const float4 b = a4[2 * s + 1];
      short8 v;
      v[0] = (short)f2bf(a.x); v[1] = (short)f2bf(a.y); v[2] = (short)f2bf(a.z); v[3] = (short)f2bf(a.w);
      v[4] = (short)f2bf(b.x); v[5] = (short)f2bf(b.y); v[6] = (short)f2bf(b.z); v[7] = (short)f2bf(b.w);
      *reinterpret_cast<short8*>(sm + s * 8) = v;
    }
  }
  __syncthreads();  // all act reads done -> safe to overwrite slab below
  const u16* pb = projF + (long)wave * 72 * 512;
  float* ob = out + (long)widx * 24576;
#pragma unroll 1
  for (int half = 0; half < 2; ++half) {
    f32x4 pacc[4][3];
#pragma unroll
    for (int i = 0; i < 4; ++i)
#pragma unroll
      for (int jn = 0; jn < 3; ++jn) pacc[i][jn] = fzero;
#pragma unroll 1
    for (int t = 0; t < 12; ++t) {
      short8 af[4];
#pragma unroll
      for (int i = 0; i < 4; ++i)
        af[i] = *reinterpret_cast<const short8*>(sm + ((t * 4 + i) * 64 + lane) * 8);
#pragma unroll
      for (int jn = 0; jn < 3; ++jn) {
        const short8 bw = *reinterpret_cast<const short8*>(pb + (t * 6 + half * 3 + jn) * 512 + lane * 8);
#pragma unroll
        for (int i = 0; i < 4; ++i) pacc[i][jn] = MFMA16(af[i], bw, pacc[i][jn]);
      }
    }
#pragma unroll
    for (int jn = 0; jn < 3; ++jn) {
      const int n = wave * 96 + (half * 3 + jn) * 16 + c16;
      const float bv = proj_b[n];
#pragma unroll
      for (int i = 0; i < 4; ++i)
#pragma unroll
        for (int r = 0; r < 4; ++r)
          ob[(long)(16 * i + 4 * q16 + r) * 384 + n] = pacc[i][jn][r] + bv;
    }
  }
}

// ================= fallback (no xF workspace): x staged via 96 KB LDS =================
__global__ __launch_bounds__(256, 1) void attn_fb(const float* __restrict__ x,
                                                  const float* __restrict__ mask,
                                                  const u16* __restrict__ qkvF,
                                                  const float* __restrict__ scales,
                                                  const float* __restrict__ bias,
                                                  const u16* __restrict__ projF,
                                                  const float* __restrict__ proj_b,
                                                  float* __restrict__ out) {
  __shared__ __align__(16) u16 sm[49152];  // 96 KB
  const int tid = threadIdx.x;
  const int wave = tid >> 6, lane = tid & 63;
  const int q16 = lane >> 4, c16 = lane & 15;
  const int widx = blockIdx.x, wm = widx & 63;
  u16* qs = sm + wave * 6144;
  u16* ks = qs + 2048;
  u16* ps = qs;
  u16* vst = qs + 4096;
  u16* xs = sm + 24576;
  const f32x4 fzero = {0.f, 0.f, 0.f, 0.f};
  {
    const float4* x4 = reinterpret_cast<const float4*>(x + (long)widx * 24576);
#pragma unroll
    for (int it = 0; it < 12; ++it) {
      const int c = it * 256 + tid;
      const float4 a = x4[2 * c];
      const float4 b = x4[2 * c + 1];
      short8 v;
      v[0] = (short)f2bf(a.x); v[1] = (short)f2bf(a.y); v[2] = (short)f2bf(a.z); v[3] = (short)f2bf(a.w);
      v[4] = (short)f2bf(b.x); v[5] = (short)f2bf(b.y); v[6] = (short)f2bf(b.z); v[7] = (short)f2bf(b.w);
      const int row = c / 48;
      *reinterpret_cast<short8*>(xs + ((c * 8) ^ ((row & 7) << 3))) = v;
    }
  }
  __syncthreads();
  unsigned ow[3][4][2][2];
#pragma unroll
  for (int hh = 0; hh < 3; ++hh) {
    const int h = wave * 3 + hh;
    const float sc = scales[h];
    const u16* hb = qkvF + (long)h * 72 * 512;
    f32x4 qa[4][2], ka[4][2], va[4][2];
#pragma unroll
    for (int i = 0; i < 4; ++i)
#pragma unroll
      for (int j = 0; j < 2; ++j) {
        qa[i][j] = fzero; ka[i][j] = fzero; va[i][j] = fzero;
      }
#pragma unroll 1
    for (int t = 0; t < 12; ++t) {
      const int k0 = t * 32 + q16 * 8;
      short8 af[4];
#pragma unroll
      for (int i = 0; i < 4; ++i) {
        const int row = c16 + 16 * i;
        af[i] = *reinterpret_cast<const short8*>(xs + ((row * 384 + k0) ^ ((row & 7) << 3)));
      }
#pragma unroll
      for (int jn = 0; jn < 2; ++jn) {
        const int fi = (2 * t + jn) * 512 + lane * 8;
        const short8 bq = *reinterpret_cast<const short8*>(hb + fi);
        const short8 bk = *reinterpret_cast<const short8*>(hb + 24 * 512 + fi);
        const short8 bv = *reinterpret_cast<const short8*>(hb + 48 * 512 + fi);
#pragma unroll
        for (int i = 0; i < 4; ++i) {
          qa[i][jn] = MFMA16(af[i], bq, qa[i][jn]);
          ka[i][jn] = MFMA16(af[i], bk, ka[i][jn]);
          va[i][jn] = MFMA16(af[i], bv, va[i][jn]);
        }
      }
    }
#pragma unroll
    for (int i = 0; i < 4; ++i) {
#pragma unroll
      for (int r = 0; r < 4; ++r) {
        const int row = 16 * i + 4 * q16 + r;
        float sq = qa[i][0][r] * qa[i][0][r] + qa[i][1][r] * qa[i][1][r];
        float sk = ka[i][0][r] * ka[i][0][r] + ka[i][1][r] * ka[i][1][r];
#pragma unroll
        for (int off = 1; off < 16; off <<= 1) {
          sq += __shfl_xor(sq, off);
          sk += __shfl_xor(sk, off);
        }
        const float rq = rsqrtf(fmaxf(sq, 1e-12f)) * sc;
        const float rk = rsqrtf(fmaxf(sk, 1e-12f));
        const int swq = (row & 3) << 3;
#pragma unroll
        for (int jn = 0; jn < 2; ++jn) {
          const int col = 16 * jn + c16;
          qs[(row * 32 + col) ^ swq] = f2bf(qa[i][jn][r] * rq);
          ks[(row * 32 + col) ^ swq] = f2bf(ka[i][jn][r] * rk);
          vst[(col * 64 + row) ^ ((col & 7) << 3)] = f2bf(va[i][jn][r]);
        }
      }
    }
    f32x4 sacc[4][4];
    {
      const float* bh = bias + h * 4096;
      const float* mw = mask + (long)wm * 4096;
#pragma unroll
      for (int i = 0; i < 4; ++i)
#pragma unroll
        for (int j = 0; j < 4; ++j) {
          const int col = 16 * j + c16;
#pragma unroll
          for (int r = 0; r < 4; ++r) {
            const int row = 16 * i + 4 * q16 + r;
            sacc[i][j][r] = bh[row * 64 + col] + mw[row * 64 + col];
          }
        }
    }
    short8 aq[4], bk4[4];
#pragma unroll
    for (int i = 0; i < 4; ++i) {
      const int row = c16 + 16 * i;
      aq[i] = *reinterpret_cast<const short8*>(qs + ((row * 32 + q16 * 8) ^ ((row & 3) << 3)));
      bk4[i] = *reinterpret_cast<const short8*>(ks + ((row * 32 + q16 * 8) ^ ((row & 3) << 3)));
    }
#pragma unroll
    for (int i = 0; i < 4; ++i)
#pragma unroll
      for (int j = 0; j < 4; ++j) sacc[i][j] = MFMA16(aq[i], bk4[j], sacc[i][j]);
#pragma unroll
    for (int i = 0; i < 4; ++i) {
#pragma unroll
      for (int r = 0; r < 4; ++r) {
        float m = fmaxf(fmaxf(sacc[i][0][r], sacc[i][1][r]), fmaxf(sacc[i][2][r], sacc[i][3][r]));
#pragma unroll
        for (int off = 1; off < 16; off <<= 1) m = fmaxf(m, __shfl_xor(m, off));
        float e[4], s = 0.f;
#pragma unroll
        for (int j = 0; j < 4; ++j) {
          e[j] = __expf(sacc[i][j][r] - m);
          s += e[j];
        }
#pragma unroll
        for (int off = 1; off < 16; off <<= 1) s += __shfl_xor(s, off);
        const float inv = 1.f / s;
        const int row = 16 * i + 4 * q16 + r;
        const int sw = (row & 7) << 3;
#pragma unroll
        for (int j = 0; j < 4; ++j) ps[(row * 64 + 16 * j + c16) ^ sw] = f2bf(e[j] * inv);
      }
    }
    f32x4 oa[4][2];
#pragma unroll
    for (int i = 0; i < 4; ++i) {
      oa[i][0] = fzero;
      oa[i][1] = fzero;
    }
#pragma unroll
    for (int kt = 0; kt < 2; ++kt) {
      short8 ap[4], bv2[2];
#pragma unroll
      for (int i = 0; i < 4; ++i) {
        const int row = c16 + 16 * i;
        ap[i] = *reinterpret_cast<const short8*>(ps + ((row * 64 + kt * 32 + q16 * 8) ^ ((row & 7) << 3)));
      }
#pragma unroll
      for (int jn = 0; jn < 2; ++jn) {
        const int d = 16 * jn + c16;
        bv2[jn] = *reinterpret_cast<const short8*>(vst + ((d * 64 + kt * 32 + q16 * 8) ^ ((d & 7) << 3)));
      }
#pragma unroll
      for (int i = 0; i < 4; ++i)
#pragma unroll
        for (int jn = 0; jn < 2; ++jn) oa[i][jn] = MFMA16(ap[i], bv2[jn], oa[i][jn]);
    }
#pragma unroll
    for (int i = 0; i < 4; ++i)
#pragma unroll
      for (int jn = 0; jn < 2; ++jn) {
        ow[hh][i][jn][0] = (unsigned)f2bf(oa[i][jn][0]) | ((unsigned)f2bf(oa[i][jn][1]) << 16);
        ow[hh][i][jn][1] = (unsigned)f2bf(oa[i][jn][2]) | ((unsigned)f2bf(oa[i][jn][3]) << 16);
      }
  }
  __syncthreads();
#pragma unroll
  for (int hh = 0; hh < 3; ++hh) {
    const int cb = (wave * 3 + hh) * 32;
#pragma unroll
    for (int i = 0; i < 4; ++i)
#pragma unroll
      for (int jn = 0; jn < 2; ++jn)
#pragma unroll
        for (int p = 0; p < 2; ++p) {
          const unsigned w = ow[hh][i][jn][p];
          const int col = cb + 16 * jn + c16;
          const int r0 = 16 * i + 4 * q16 + 2 * p;
          xs[(r0 * 384 + col) ^ ((r0 & 7) << 3)] = (u16)(w & 0xffffu);
          xs[((r0 + 1) * 384 + col) ^ (((r0 + 1) & 7) << 3)] = (u16)(w >> 16);
        }
  }
  __syncthreads();
  const u16* pb = projF + (long)wave * 72 * 512;
  f32x4 pacc[4][6];
#pragma unroll
  for (int i = 0; i < 4; ++i)
#pragma unroll
    for (int jn = 0; jn < 6; ++jn) pacc[i][jn] = fzero;
#pragma unroll 1
  for (int t = 0; t < 12; ++t) {
    const int k0 = t * 32 + q16 * 8;
    short8 af[4];
#pragma unroll
    for (int i = 0; i < 4; ++i) {
      const int row = c16 + 16 * i;
      af[i] = *reinterpret_cast<const short8*>(xs + ((row * 384 + k0) ^ ((row & 7) << 3)));
    }
#pragma unroll
    for (int jn = 0; jn < 6; ++jn) {
      const short8 bw = *reinterpret_cast<const short8*>(pb + (t * 6 + jn) * 512 + lane * 8);
#pragma unroll
      for (int i = 0; i < 4; ++i) pacc[i][jn] = MFMA16(af[i], bw, pacc[i][jn]);
    }
  }
  float* ob = out + (long)widx * 24576;
#pragma unroll
  for (int jn = 0; jn < 6; ++jn) {
    const int n = wave * 96 + 16 * jn + c16;
    const float bv = proj_b[n];
#pragma unroll
    for (int i = 0; i < 4; ++i)
#pragma unroll
      for (int r = 0; r < 4; ++r)
        ob[(long)(16 * i + 4 * q16 + r) * 384 + n] = pacc[i][jn][r] + bv;
  }
}

extern "C" void kernel_launch(void* const* d_in, const int* in_sizes, int n_in, void* d_out,
                              int out_size, void* d_ws, size_t ws_size, hipStream_t stream) {
  const float* x = (const float*)d_in[0];
  const float* mask = (const float*)d_in[1];
  const float* qkv_w = (const float*)d_in[2];
  const float* proj_w = (const float*)d_in[3];
  const float* proj_b = (const float*)d_in[4];
  const float* cpb_w1 = (const float*)d_in[5];
  const float* cpb_b1 = (const float*)d_in[6];
  const float* cpb_w2 = (const float*)d_in[7];
  const float* cpb_b2 = (const float*)d_in[8];
  const float* logit_scale = (const float*)d_in[9];
  const float* rpb_table = (const float*)d_in[10];
  const int* rpb_idx = (const int*)d_in[11];

  char* ws = (char*)d_ws;
  float* bias = (float*)(ws + OFF_BIAS);
  float* scales = (float*)(ws + OFF_SCALES);
  float* rpb = (float*)(ws + OFF_RPB);
  u16* qkvF = (u16*)(ws + OFF_QKVF);
  u16* projF = (u16*)(ws + OFF_PROJF);
  u16* xF = (u16*)(ws + OFF_XF);

  prep_cpb<<<225, 256, 0, stream>>>(rpb_table, cpb_w1, cpb_b1, cpb_w2, cpb_b2, rpb);
  const bool big = ws_size >= WS_NEED;
  if (big) {
    prep_all<<<1185, 256, 0, stream>>>(x, qkv_w, proj_w, logit_scale, rpb, rpb_idx,
                                       xF, qkvF, projF, scales, bias, 0);
    attn1<<<3072, 256, 0, stream>>>(xF, mask, qkvF, scales, bias, (float*)d_out);
    proj2<<<1024, 256, 0, stream>>>((const float*)d_out, projF, proj_b, (float*)d_out);
  } else {
    prep_all<<<161, 256, 0, stream>>>(x, qkv_w, proj_w, logit_scale, rpb, rpb_idx,
                                      xF, qkvF, projF, scales, bias, 1024);
    attn_fb<<<1024, 256, 0, stream>>>(x, mask, qkvF, scales, bias, projF, proj_b, (float*)d_out);
  }
}

// Round 11
// 343.713 us; speedup vs baseline: 1.4721x; 1.0439x over previous
//
#include <hip/hip_runtime.h>

typedef unsigned short u16;
typedef __attribute__((ext_vector_type(8))) short short8;
typedef __attribute__((ext_vector_type(4))) float f32x4;

#define MFMA16(a, b, c) __builtin_amdgcn_mfma_f32_16x16x32_bf16((a), (b), (c), 0, 0, 0)

// ---- workspace layout (bytes) ----
#define OFF_BIAS 0            // fp32 [12][64][64]      = 196608
#define OFF_SCALES 196608     // fp32 [12]              (64 B slot)
#define OFF_RPB 196672        // fp32 [225][12]         = 10800 (slot to 207616)
#define OFF_QKVF 207616       // bf16 frag-ordered qkv weights = 884736
#define OFF_PROJF 1092352     // bf16 frag-ordered proj weights = 294912 (end 1387264)
#define OFF_XF 1387264        // bf16 fragment-ordered x: 1024 * 24576 u16 = 50331648
#define WS_NEED (1387264UL + 50331648UL)

// qkvF layout: frag(h,m,t,jn) at ((h*3+m)*24 + 2*t + jn)*512 + lane*8   (u16 units)
// projF layout: frag(w,t,jn)  at (w*72 + t*6 + jn)*512 + lane*8   (w=n16/6, jn=n16%6)
// xF layout:    frag(t,i)     at ((t*4+i)*64 + lane)*8  within window slab of 24576

__device__ __forceinline__ u16 f2bf(float f) {
  unsigned x = __float_as_uint(f);
  return (u16)((x + 0x7fffu + ((x >> 16) & 1u)) >> 16);  // RNE, finite values only
}

// ================= prep: CPB MLP, one block per table entry (225 blocks) =================
__global__ __launch_bounds__(256) void prep_cpb(const float* __restrict__ tab, const float* __restrict__ w1,
                                                const float* __restrict__ b1, const float* __restrict__ w2,
                                                const float* __restrict__ b2, float* __restrict__ rpb) {
  const int t = blockIdx.x;   // 0..224
  const int tid = threadIdx.x;
  const float t0 = tab[2 * t], t1 = tab[2 * t + 1];
  float acc[12];
#pragma unroll
  for (int h = 0; h < 12; ++h) acc[h] = 0.f;
  for (int j = tid; j < 512; j += 256) {
    const float hv = fmaxf(t0 * w1[j] + t1 * w1[512 + j] + b1[j], 0.f);
#pragma unroll
    for (int h = 0; h < 12; ++h) acc[h] += hv * w2[j * 12 + h];
  }
#pragma unroll
  for (int h = 0; h < 12; ++h)
#pragma unroll
    for (int off = 1; off < 64; off <<= 1) acc[h] += __shfl_xor(acc[h], off);
  __shared__ float red[4][12];
  const int wave = tid >> 6;
  if ((tid & 63) == 0) {
#pragma unroll
    for (int h = 0; h < 12; ++h) red[wave][h] = acc[h];
  }
  __syncthreads();
  if (tid < 12) rpb[t * 12 + tid] = red[0][tid] + red[1][tid] + red[2][tid] + red[3][tid] + b2[tid];
}

// ================= unified prep =================
__global__ __launch_bounds__(256) void prep_all(const float* __restrict__ x,
                                                const float* __restrict__ qkv_w,
                                                const float* __restrict__ proj_w,
                                                const float* __restrict__ logit_scale,
                                                const float* __restrict__ rpb,
                                                const int* __restrict__ rpb_idx,
                                                u16* __restrict__ xF, u16* __restrict__ qkvF,
                                                u16* __restrict__ projF, float* __restrict__ scales,
                                                float* __restrict__ bias, int bid0) {
  __shared__ __align__(16) u16 sm[24576];  // 48 KB, unioned per branch
  const int bid = blockIdx.x + bid0;
  const int tid = threadIdx.x;
  if (bid < 1024) {
    // ---- stage x window (fp32 -> bf16, swizzled, coalesced) ----
    const float4* x4 = reinterpret_cast<const float4*>(x + (long)bid * 24576);
#pragma unroll
    for (int it = 0; it < 12; ++it) {
      const int c = it * 256 + tid;  // 8-u16 chunk id, 0..3071
      const float4 a = x4[2 * c];
      const float4 b = x4[2 * c + 1];
      short8 v;
      v[0] = (short)f2bf(a.x); v[1] = (short)f2bf(a.y); v[2] = (short)f2bf(a.z); v[3] = (short)f2bf(a.w);
      v[4] = (short)f2bf(b.x); v[5] = (short)f2bf(b.y); v[6] = (short)f2bf(b.z); v[7] = (short)f2bf(b.w);
      const int row = c / 48;
      *reinterpret_cast<short8*>(sm + ((c * 8) ^ ((row & 7) << 3))) = v;
    }
    __syncthreads();
    // ---- emit fragment-ordered (coalesced writes) ----
    u16* dst = xF + (long)bid * 24576;
#pragma unroll
    for (int it = 0; it < 12; ++it) {
      const int slot = it * 256 + tid;           // 0..3071 = 48 frags x 64 lanes
      const int f = slot >> 6, l = slot & 63;
      const int row = 16 * (f & 3) + (l & 15);
      const int k0 = (f >> 2) * 32 + (l >> 4) * 8;
      const short8 v = *reinterpret_cast<const short8*>(sm + ((row * 384 + k0) ^ ((row & 7) << 3)));
      *reinterpret_cast<short8*>(dst + slot * 8) = v;
    }
  } else if (bid < 1168) {
    u16(*tile)[66] = reinterpret_cast<u16(*)[66]>(sm);  // pad 66: column reads 2-way (free)
    const float* src;
    int W, rt, ct;
    const bool isqkv = bid < 1132;
    if (isqkv) {
      const int b = bid - 1024;
      src = qkv_w; W = 1152; rt = b / 18; ct = b % 18;
    } else {
      const int b = bid - 1132;
      src = proj_w; W = 384; rt = b / 6; ct = b % 6;
    }
#pragma unroll
    for (int kk = 0; kk < 4; ++kk) {
      const int idx = tid + kk * 256;
      const int r = idx >> 4, c4 = idx & 15;
      const float4 v = *reinterpret_cast<const float4*>(src + (long)(rt * 64 + r) * W + ct * 64 + c4 * 4);
      tile[r][c4 * 4 + 0] = f2bf(v.x);
      tile[r][c4 * 4 + 1] = f2bf(v.y);
      tile[r][c4 * 4 + 2] = f2bf(v.z);
      tile[r][c4 * 4 + 3] = f2bf(v.w);
    }
    __syncthreads();
#pragma unroll
    for (int kk = 0; kk < 4; ++kk) {
      const int idx = tid + kk * 256;
      const int c = idx >> 4, r0 = (idx & 15) * 4;
      ushort4 o;
      o.x = tile[r0 + 0][c];
      o.y = tile[r0 + 1][c];
      o.z = tile[r0 + 2][c];
      o.w = tile[r0 + 3][c];
      const int col = ct * 64 + c, k = rt * 64 + r0;
      const int lane = ((k >> 3) & 3) * 16 + (col & 15);
      const int e = k & 7;  // 0 or 4
      long off;
      if (isqkv) {
        const int m = col / 384, colm = col - m * 384;
        const int h = colm >> 5, jn = (colm >> 4) & 1;
        off = (long)(((h * 3 + m) * 24) + (k >> 5) * 2 + jn) * 512 + lane * 8 + e;
        *reinterpret_cast<ushort4*>(qkvF + off) = o;
      } else {
        const int w = col / 96, colw = col - w * 96;
        const int jn = colw >> 4;
        off = (long)(w * 72 + (k >> 5) * 6 + jn) * 512 + lane * 8 + e;
        *reinterpret_cast<ushort4*>(projF + off) = o;
      }
    }
  } else if (bid == 1168) {
    if (tid < 12) scales[tid] = __expf(fminf(logit_scale[tid], 4.6051702f));
  } else {
    const int p = (bid - 1169) * 256 + tid;  // 0..4095
    const int t = rpb_idx[p];
#pragma unroll
    for (int h = 0; h < 12; ++h) bias[h * 4096 + p] = 16.f / (1.f + __expf(-rpb[t * 12 + h]));
  }
}

// ================= fused attention + projection: 1 block = 1 window, 12 waves =================
// Wave w = head w, fully private 12 KB LDS region (R10's proven per-wave structure; no
// barriers in the attn phase). Per-head O goes bf16 into the wave's own (dead) qs area;
// ONE __syncthreads; then proj K-fragment t == head t's O tile, read in place. Eliminates
// proj2 kernel + the 192 MB act round-trip. LDS 144 KB -> 1 block/CU, 12 waves/CU.
// __launch_bounds__(768): 12-wave block forces compiler cap <= ~168 VGPR (3 waves/EU).
__global__ __launch_bounds__(768) void attn_fused(const u16* __restrict__ xF,
                                                  const float* __restrict__ mask,
                                                  const u16* __restrict__ qkvF,
                                                  const float* __restrict__ scales,
                                                  const float* __restrict__ bias,
                                                  const u16* __restrict__ projF,
                                                  const float* __restrict__ proj_b,
                                                  float* __restrict__ out) {
  __shared__ __align__(16) u16 sm[73728];  // 144 KB = 12 waves x 12 KB private
  const int tid = threadIdx.x;
  const int wave = tid >> 6, lane = tid & 63;
  const int q16 = lane >> 4, c16 = lane & 15;
  const int widx = blockIdx.x, wm = widx & 63;
  const int h = wave;
  u16* qs = sm + wave * 6144;   // [64][32] swz(row&3); later: O tile (same layout)
  u16* ks = qs + 2048;          // [64][32] swz(row&3)
  u16* ps = qs;                 // [64][64] swz(row&7), overlays qs+ks (frags preloaded)
  u16* vst = qs + 4096;         // [32 d][64 tok] swz(d&7)
  const u16* xw = xF + (long)widx * 24576;
  const u16* hb = qkvF + (long)h * 72 * 512;
  const float sc = scales[h];
  const f32x4 fzero = {0.f, 0.f, 0.f, 0.f};

  // ---- Pass QK: q,k = x_w @ Wq,Wk (64 accumulators) ----
  {
    f32x4 qa[4][2], ka[4][2];
#pragma unroll
    for (int i = 0; i < 4; ++i)
#pragma unroll
      for (int j = 0; j < 2; ++j) {
        qa[i][j] = fzero; ka[i][j] = fzero;
      }
#pragma unroll 1
    for (int t = 0; t < 12; ++t) {
      short8 af[4];
#pragma unroll
      for (int i = 0; i < 4; ++i)
        af[i] = *reinterpret_cast<const short8*>(xw + ((t * 4 + i) * 64 + lane) * 8);
#pragma unroll
      for (int jn = 0; jn < 2; ++jn) {
        const int fi = (2 * t + jn) * 512 + lane * 8;
        const short8 bq = *reinterpret_cast<const short8*>(hb + fi);
        const short8 bk = *reinterpret_cast<const short8*>(hb + 24 * 512 + fi);
#pragma unroll
        for (int i = 0; i < 4; ++i) {
          qa[i][jn] = MFMA16(af[i], bq, qa[i][jn]);
          ka[i][jn] = MFMA16(af[i], bk, ka[i][jn]);
        }
      }
    }
    // normalize q (x scale) and k; stage qs/ks; kills qa/ka
    // C/D layout: col = lane&15, row = (lane>>4)*4 + reg
#pragma unroll
    for (int i = 0; i < 4; ++i) {
#pragma unroll
      for (int r = 0; r < 4; ++r) {
        const int row = 16 * i + 4 * q16 + r;
        float sq = qa[i][0][r] * qa[i][0][r] + qa[i][1][r] * qa[i][1][r];
        float sk = ka[i][0][r] * ka[i][0][r] + ka[i][1][r] * ka[i][1][r];
#pragma unroll
        for (int off = 1; off < 16; off <<= 1) {
          sq += __shfl_xor(sq, off);
          sk += __shfl_xor(sk, off);
        }
        const float rq = rsqrtf(fmaxf(sq, 1e-12f)) * sc;
        const float rk = rsqrtf(fmaxf(sk, 1e-12f));
        const int swq = (row & 3) << 3;
#pragma unroll
        for (int jn = 0; jn < 2; ++jn) {
          const int col = 16 * jn + c16;
          qs[(row * 32 + col) ^ swq] = f2bf(qa[i][jn][r] * rq);
          ks[(row * 32 + col) ^ swq] = f2bf(ka[i][jn][r] * rk);
        }
      }
    }
  }
  __builtin_amdgcn_sched_barrier(0);
  // ---- Pass V: v = x_w @ Wv (32 accumulators), stage v^T ----
  {
    f32x4 va[4][2];
#pragma unroll
    for (int i = 0; i < 4; ++i) {
      va[i][0] = fzero;
      va[i][1] = fzero;
    }
#pragma unroll 1
    for (int t = 0; t < 12; ++t) {
      short8 af[4];
#pragma unroll
      for (int i = 0; i < 4; ++i)
        af[i] = *reinterpret_cast<const short8*>(xw + ((t * 4 + i) * 64 + lane) * 8);
#pragma unroll
      for (int jn = 0; jn < 2; ++jn) {
        const short8 bv = *reinterpret_cast<const short8*>(hb + 48 * 512 + (2 * t + jn) * 512 + lane * 8);
#pragma unroll
        for (int i = 0; i < 4; ++i) va[i][jn] = MFMA16(af[i], bv, va[i][jn]);
      }
    }
#pragma unroll
    for (int i = 0; i < 4; ++i)
#pragma unroll
      for (int jn = 0; jn < 2; ++jn) {
        const int d = 16 * jn + c16;
        ushort4 vv;
        vv.x = f2bf(va[i][jn][0]);
        vv.y = f2bf(va[i][jn][1]);
        vv.z = f2bf(va[i][jn][2]);
        vv.w = f2bf(va[i][jn][3]);
        *reinterpret_cast<ushort4*>(vst + ((d * 64 + 16 * i + 4 * q16) ^ ((d & 7) << 3))) = vv;
      }
  }
  __builtin_amdgcn_sched_barrier(0);
  // ---- preload S-operand fragments (qs/ks then dead -> ps overlay / O-tile reuse safe) ----
  short8 aq[4], bk4[4];
#pragma unroll
  for (int i = 0; i < 4; ++i) {
    const int row = c16 + 16 * i;
    aq[i] = *reinterpret_cast<const short8*>(qs + ((row * 32 + q16 * 8) ^ ((row & 3) << 3)));
    bk4[i] = *reinterpret_cast<const short8*>(ks + ((row * 32 + q16 * 8) ^ ((row & 3) << 3)));
  }
  __builtin_amdgcn_sched_barrier(0);
  // ---- chunked C/D/E: 4 independent 16-row groups; O bf16 lands in the qs area ----
  // Byte audit: chunk i writes/reads ps band i = region bytes [2048i, 2048i+2048); the
  // O band i = bytes [1024i, 1024i+1024) only touches ps bands floor(i/2) <= i already
  // consumed -> safe to write after chunk i's PV.
  const float* bh = bias + h * 4096;
  const float* mw = mask + (long)wm * 4096;
#pragma unroll
  for (int i = 0; i < 4; ++i) {
    // C: S rows = bias + mask, then QK^T
    f32x4 si[4];
#pragma unroll
    for (int j = 0; j < 4; ++j) {
      const int col = 16 * j + c16;
#pragma unroll
      for (int r = 0; r < 4; ++r) {
        const int row = 16 * i + 4 * q16 + r;
        si[j][r] = bh[row * 64 + col] + mw[row * 64 + col];
      }
    }
#pragma unroll
    for (int j = 0; j < 4; ++j) si[j] = MFMA16(aq[i], bk4[j], si[j]);
    // D: softmax over keys for these 16 rows, write ps rows
#pragma unroll
    for (int r = 0; r < 4; ++r) {
      float m = fmaxf(fmaxf(si[0][r], si[1][r]), fmaxf(si[2][r], si[3][r]));
#pragma unroll
      for (int off = 1; off < 16; off <<= 1) m = fmaxf(m, __shfl_xor(m, off));
      float e[4], s = 0.f;
#pragma unroll
      for (int j = 0; j < 4; ++j) {
        e[j] = __expf(si[j][r] - m);
        s += e[j];
      }
#pragma unroll
      for (int off = 1; off < 16; off <<= 1) s += __shfl_xor(s, off);
      const float inv = 1.f / s;
      const int row = 16 * i + 4 * q16 + r;
      const int sw = (row & 7) << 3;
#pragma unroll
      for (int j = 0; j < 4; ++j) ps[(row * 64 + 16 * j + c16) ^ sw] = f2bf(e[j] * inv);
    }
    // E: O rows for this group = P rows @ V
    f32x4 oi[2];
    oi[0] = fzero;
    oi[1] = fzero;
    const int rowp = c16 + 16 * i;
#pragma unroll
    for (int kt = 0; kt < 2; ++kt) {
      const short8 api = *reinterpret_cast<const short8*>(
          ps + ((rowp * 64 + kt * 32 + q16 * 8) ^ ((rowp & 7) << 3)));
#pragma unroll
      for (int jn = 0; jn < 2; ++jn) {
        const int d = 16 * jn + c16;
        const short8 bvf = *reinterpret_cast<const short8*>(
            vst + ((d * 64 + kt * 32 + q16 * 8) ^ ((d & 7) << 3)));
        oi[jn] = MFMA16(api, bvf, oi[jn]);
      }
    }
    // O bf16 into the wave's own qs-area tile [64 tok][32 dim] swz(row&3)
#pragma unroll
    for (int jn = 0; jn < 2; ++jn)
#pragma unroll
      for (int r = 0; r < 4; ++r) {
        const int row = 16 * i + 4 * q16 + r;
        qs[(row * 32 + 16 * jn + c16) ^ ((row & 3) << 3)] = f2bf(oi[jn][r]);
      }
    __builtin_amdgcn_sched_barrier(0);  // pin chunk boundary
  }
  __syncthreads();  // all 12 heads' O tiles visible block-wide
  // ---- fused projection: out = act @ projF + b; K-frag t == head t's O tile ----
  // Wave handles output cols n16 = wave*2 + jnp (32 cols).
  const int n16a = wave * 2, n16b = wave * 2 + 1;
  const u16* pba = projF + (long)((n16a / 6) * 72 + (n16a % 6)) * 512;
  const u16* pbb = projF + (long)((n16b / 6) * 72 + (n16b % 6)) * 512;
  f32x4 pacc[4][2];
#pragma unroll
  for (int i = 0; i < 4; ++i) {
    pacc[i][0] = fzero;
    pacc[i][1] = fzero;
  }
#pragma unroll 1
  for (int t = 0; t < 12; ++t) {
    const u16* reg = sm + t * 6144;  // head t's O tile
    short8 af[4];
#pragma unroll
    for (int i = 0; i < 4; ++i) {
      const int row = c16 + 16 * i;
      af[i] = *reinterpret_cast<const short8*>(reg + ((row * 32 + q16 * 8) ^ ((row & 3) << 3)));
    }
    const short8 bwa = *reinterpret_cast<const short8*>(pba + (long)t * 6 * 512 + lane * 8);
    const short8 bwb = *reinterpret_cast<const short8*>(pbb + (long)t * 6 * 512 + lane * 8);
#pragma unroll
    for (int i = 0; i < 4; ++i) {
      pacc[i][0] = MFMA16(af[i], bwa, pacc[i][0]);
      pacc[i][1] = MFMA16(af[i], bwb, pacc[i][1]);
    }
  }
  float* ob = out + (long)widx * 24576;
#pragma unroll
  for (int jnp = 0; jnp < 2; ++jnp) {
    const int n = (wave * 2 + jnp) * 16 + c16;
    const float bv = proj_b[n];
#pragma unroll
    for (int i = 0; i < 4; ++i)
#pragma unroll
      for (int r = 0; r < 4; ++r)
        ob[(long)(16 * i + 4 * q16 + r) * 384 + n] = pacc[i][jnp][r] + bv;
  }
}

// ================= fallback (no xF workspace): x staged via 96 KB LDS =================
__global__ __launch_bounds__(256, 1) void attn_fb(const float* __restrict__ x,
                                                  const float* __restrict__ mask,
                                                  const u16* __restrict__ qkvF,
                                                  const float* __restrict__ scales,
                                                  const float* __restrict__ bias,
                                                  const u16* __restrict__ projF,
                                                  const float* __restrict__ proj_b,
                                                  float* __restrict__ out) {
  __shared__ __align__(16) u16 sm[49152];  // 96 KB
  const int tid = threadIdx.x;
  const int wave = tid >> 6, lane = tid & 63;
  const int q16 = lane >> 4, c16 = lane & 15;
  const int widx = blockIdx.x, wm = widx & 63;
  u16* qs = sm + wave * 6144;
  u16* ks = qs + 2048;
  u16* ps = qs;
  u16* vst = qs + 4096;
  u16* xs = sm + 24576;
  const f32x4 fzero = {0.f, 0.f, 0.f, 0.f};
  {
    const float4* x4 = reinterpret_cast<const float4*>(x + (long)widx * 24576);
#pragma unroll
    for (int it = 0; it < 12; ++it) {
      const int c = it * 256 + tid;
      const float4 a = x4[2 * c];
      const float4 b = x4[2 * c + 1];
      short8 v;
      v[0] = (short)f2bf(a.x); v[1] = (short)f2bf(a.y); v[2] = (short)f2bf(a.z); v[3] = (short)f2bf(a.w);
      v[4] = (short)f2bf(b.x); v[5] = (short)f2bf(b.y); v[6] = (short)f2bf(b.z); v[7] = (short)f2bf(b.w);
      const int row = c / 48;
      *reinterpret_cast<short8*>(xs + ((c * 8) ^ ((row & 7) << 3))) = v;
    }
  }
  __syncthreads();
  unsigned ow[3][4][2][2];
#pragma unroll
  for (int hh = 0; hh < 3; ++hh) {
    const int h = wave * 3 + hh;
    const float sc = scales[h];
    const u16* hb = qkvF + (long)h * 72 * 512;
    f32x4 qa[4][2], ka[4][2], va[4][2];
#pragma unroll
    for (int i = 0; i < 4; ++i)
#pragma unroll
      for (int j = 0; j < 2; ++j) {
        qa[i][j] = fzero; ka[i][j] = fzero; va[i][j] = fzero;
      }
#pragma unroll 1
    for (int t = 0; t < 12; ++t) {
      const int k0 = t * 32 + q16 * 8;
      short8 af[4];
#pragma unroll
      for (int i = 0; i < 4; ++i) {
        const int row = c16 + 16 * i;
        af[i] = *reinterpret_cast<const short8*>(xs + ((row * 384 + k0) ^ ((row & 7) << 3)));
      }
#pragma unroll
      for (int jn = 0; jn < 2; ++jn) {
        const int fi = (2 * t + jn) * 512 + lane * 8;
        const short8 bq = *reinterpret_cast<const short8*>(hb + fi);
        const short8 bk = *reinterpret_cast<const short8*>(hb + 24 * 512 + fi);
        const short8 bv = *reinterpret_cast<const short8*>(hb + 48 * 512 + fi);
#pragma unroll
        for (int i = 0; i < 4; ++i) {
          qa[i][jn] = MFMA16(af[i], bq, qa[i][jn]);
          ka[i][jn] = MFMA16(af[i], bk, ka[i][jn]);
          va[i][jn] = MFMA16(af[i], bv, va[i][jn]);
        }
      }
    }
#pragma unroll
    for (int i = 0; i < 4; ++i) {
#pragma unroll
      for (int r = 0; r < 4; ++r) {
        const int row = 16 * i + 4 * q16 + r;
        float sq = qa[i][0][r] * qa[i][0][r] + qa[i][1][r] * qa[i][1][r];
        float sk = ka[i][0][r] * ka[i][0][r] + ka[i][1][r] * ka[i][1][r];
#pragma unroll
        for (int off = 1; off < 16; off <<= 1) {
          sq += __shfl_xor(sq, off);
          sk += __shfl_xor(sk, off);
        }
        const float rq = rsqrtf(fmaxf(sq, 1e-12f)) * sc;
        const float rk = rsqrtf(fmaxf(sk, 1e-12f));
        const int swq = (row & 3) << 3;
#pragma unroll
        for (int jn = 0; jn < 2; ++jn) {
          const int col = 16 * jn + c16;
          qs[(row * 32 + col) ^ swq] = f2bf(qa[i][jn][r] * rq);
          ks[(row * 32 + col) ^ swq] = f2bf(ka[i][jn][r] * rk);
          vst[(col * 64 + row) ^ ((col & 7) << 3)] = f2bf(va[i][jn][r]);
        }
      }
    }
    f32x4 sacc[4][4];
    {
      const float* bh = bias + h * 4096;
      const float* mw = mask + (long)wm * 4096;
#pragma unroll
      for (int i = 0; i < 4; ++i)
#pragma unroll
        for (int j = 0; j < 4; ++j) {
          const int col = 16 * j + c16;
#pragma unroll
          for (int r = 0; r < 4; ++r) {
            const int row = 16 * i + 4 * q16 + r;
            sacc[i][j][r] = bh[row * 64 + col] + mw[row * 64 + col];
          }
        }
    }
    short8 aq[4], bk4[4];
#pragma unroll
    for (int i = 0; i < 4; ++i) {
      const int row = c16 + 16 * i;
      aq[i] = *reinterpret_cast<const short8*>(qs + ((row * 32 + q16 * 8) ^ ((row & 3) << 3)));
      bk4[i] = *reinterpret_cast<const short8*>(ks + ((row * 32 + q16 * 8) ^ ((row & 3) << 3)));
    }
#pragma unroll
    for (int i = 0; i < 4; ++i)
#pragma unroll
      for (int j = 0; j < 4; ++j) sacc[i][j] = MFMA16(aq[i], bk4[j], sacc[i][j]);
#pragma unroll
    for (int i = 0; i < 4; ++i) {
#pragma unroll
      for (int r = 0; r < 4; ++r) {
        float m = fmaxf(fmaxf(sacc[i][0][r], sacc[i][1][r]), fmaxf(sacc[i][2][r], sacc[i][3][r]));
#pragma unroll
        for (int off = 1; off < 16; off <<= 1) m = fmaxf(m, __shfl_xor(m, off));
        float e[4], s = 0.f;
#pragma unroll
        for (int j = 0; j < 4; ++j) {
          e[j] = __expf(sacc[i][j][r] - m);
          s += e[j];
        }
#pragma unroll
        for (int off = 1; off < 16; off <<= 1) s += __shfl_xor(s, off);
        const float inv = 1.f / s;
        const int row = 16 * i + 4 * q16 + r;
        const int sw = (row & 7) << 3;
#pragma unroll
        for (int j = 0; j < 4; ++j) ps[(row * 64 + 16 * j + c16) ^ sw] = f2bf(e[j] * inv);
      }
    }
    f32x4 oa[4][2];
#pragma unroll
    for (int i = 0; i < 4; ++i) {
      oa[i][0] = fzero;
      oa[i][1] = fzero;
    }
#pragma unroll
    for (int kt = 0; kt < 2; ++kt) {
      short8 ap[4], bv2[2];
#pragma unroll
      for (int i = 0; i < 4; ++i) {
        const int row = c16 + 16 * i;
        ap[i] = *reinterpret_cast<const short8*>(ps + ((row * 64 + kt * 32 + q16 * 8) ^ ((row & 7) << 3)));
      }
#pragma unroll
      for (int jn = 0; jn < 2; ++jn) {
        const int d = 16 * jn + c16;
        bv2[jn] = *reinterpret_cast<const short8*>(vst + ((d * 64 + kt * 32 + q16 * 8) ^ ((d & 7) << 3)));
      }
#pragma unroll
      for (int i = 0; i < 4; ++i)
#pragma unroll
        for (int jn = 0; jn < 2; ++jn) oa[i][jn] = MFMA16(ap[i], bv2[jn], oa[i][jn]);
    }
#pragma unroll
    for (int i = 0; i < 4; ++i)
#pragma unroll
      for (int jn = 0; jn < 2; ++jn) {
        ow[hh][i][jn][0] = (unsigned)f2bf(oa[i][jn][0]) | ((unsigned)f2bf(oa[i][jn][1]) << 16);
        ow[hh][i][jn][1] = (unsigned)f2bf(oa[i][jn][2]) | ((unsigned)f2bf(oa[i][jn][3]) << 16);
      }
  }
  __syncthreads();
#pragma unroll
  for (int hh = 0; hh < 3; ++hh) {
    const int cb = (wave * 3 + hh) * 32;
#pragma unroll
    for (int i = 0; i < 4; ++i)
#pragma unroll
      for (int jn = 0; jn < 2; ++jn)
#pragma unroll
        for (int p = 0; p < 2; ++p) {
          const unsigned w = ow[hh][i][jn][p];
          const int col = cb + 16 * jn + c16;
          const int r0 = 16 * i + 4 * q16 + 2 * p;
          xs[(r0 * 384 + col) ^ ((r0 & 7) << 3)] = (u16)(w & 0xffffu);
          xs[((r0 + 1) * 384 + col) ^ (((r0 + 1) & 7) << 3)] = (u16)(w >> 16);
        }
  }
  __syncthreads();
  const u16* pb = projF + (long)wave * 72 * 512;
  f32x4 pacc[4][6];
#pragma unroll
  for (int i = 0; i < 4; ++i)
#pragma unroll
    for (int jn = 0; jn < 6; ++jn) pacc[i][jn] = fzero;
#pragma unroll 1
  for (int t = 0; t < 12; ++t) {
    const int k0 = t * 32 + q16 * 8;
    short8 af[4];
#pragma unroll
    for (int i = 0; i < 4; ++i) {
      const int row = c16 + 16 * i;
      af[i] = *reinterpret_cast<const short8*>(xs + ((row * 384 + k0) ^ ((row & 7) << 3)));
    }
#pragma unroll
    for (int jn = 0; jn < 6; ++jn) {
      const short8 bw = *reinterpret_cast<const short8*>(pb + (t * 6 + jn) * 512 + lane * 8);
#pragma unroll
      for (int i = 0; i < 4; ++i) pacc[i][jn] = MFMA16(af[i], bw, pacc[i][jn]);
    }
  }
  float* ob = out + (long)widx * 24576;
#pragma unroll
  for (int jn = 0; jn < 6; ++jn) {
    const int n = wave * 96 + 16 * jn + c16;
    const float bv = proj_b[n];
#pragma unroll
    for (int i = 0; i < 4; ++i)
#pragma unroll
      for (int r = 0; r < 4; ++r)
        ob[(long)(16 * i + 4 * q16 + r) * 384 + n] = pacc[i][jn][r] + bv;
  }
}

extern "C" void kernel_launch(void* const* d_in, const int* in_sizes, int n_in, void* d_out,
                              int out_size, void* d_ws, size_t ws_size, hipStream_t stream) {
  const float* x = (const float*)d_in[0];
  const float* mask = (const float*)d_in[1];
  const float* qkv_w = (const float*)d_in[2];
  const float* proj_w = (const float*)d_in[3];
  const float* proj_b = (const float*)d_in[4];
  const float* cpb_w1 = (const float*)d_in[5];
  const float* cpb_b1 = (const float*)d_in[6];
  const float* cpb_w2 = (const float*)d_in[7];
  const float* cpb_b2 = (const float*)d_in[8];
  const float* logit_scale = (const float*)d_in[9];
  const float* rpb_table = (const float*)d_in[10];
  const int* rpb_idx = (const int*)d_in[11];

  char* ws = (char*)d_ws;
  float* bias = (float*)(ws + OFF_BIAS);
  float* scales = (float*)(ws + OFF_SCALES);
  float* rpb = (float*)(ws + OFF_RPB);
  u16* qkvF = (u16*)(ws + OFF_QKVF);
  u16* projF = (u16*)(ws + OFF_PROJF);
  u16* xF = (u16*)(ws + OFF_XF);

  prep_cpb<<<225, 256, 0, stream>>>(rpb_table, cpb_w1, cpb_b1, cpb_w2, cpb_b2, rpb);
  const bool big = ws_size >= WS_NEED;
  if (big) {
    prep_all<<<1185, 256, 0, stream>>>(x, qkv_w, proj_w, logit_scale, rpb, rpb_idx,
                                       xF, qkvF, projF, scales, bias, 0);
    attn_fused<<<1024, 768, 0, stream>>>(xF, mask, qkvF, scales, bias, projF, proj_b,
                                         (float*)d_out);
  } else {
    prep_all<<<161, 256, 0, stream>>>(x, qkv_w, proj_w, logit_scale, rpb, rpb_idx,
                                      xF, qkvF, projF, scales, bias, 1024);
    attn_fb<<<1024, 256, 0, stream>>>(x, mask, qkvF, scales, bias, projF, proj_b, (float*)d_out);
  }
}